// Round 1
// baseline (55.779 us; speedup 1.0000x reference)
//
#include <hip/hip_runtime.h>

// GCLSTM (K=1 Cheb, H0=C0=0) fused kernel for MI355X.
// Math: i=sig(x@Wi+bi'), t=tanh(x@Wc+bc'), C=i*t, o=sig(x@Wo+bo'+wco*C),
//       out = (o*tanh(C)) @ fcW + fcb.  edge_index/batch/Wg_*/W_f unused.

typedef __attribute__((ext_vector_type(8))) short short8;
typedef __attribute__((ext_vector_type(4))) short short4_t;
typedef __attribute__((ext_vector_type(4))) float f32x4;

#define N_ROWS 200000
#define IN_DIM 64
#define HID 128
#define OUT_DIM 64

// ws layout (bytes)
#define WFRAG_ELEMS (24 * 2 * 64 * 8)   // 24576 bf16
#define FCFRAG_OFF  49152               // WFRAG_ELEMS*2
#define FCFRAG_ELEMS (4 * 4 * 64 * 8)   // 8192 bf16
#define BIAS_OFF    65536               // floats: bi[128],bc[128],bo[128],wco[128],fcb[64]

__device__ __forceinline__ short f2bf(float f) {
  unsigned u = __float_as_uint(f);
  u += 0x7FFFu + ((u >> 16) & 1u);   // RNE
  return (short)(u >> 16);
}
__device__ __forceinline__ float fexp2(float z) { return __builtin_amdgcn_exp2f(z); }
__device__ __forceinline__ float frcp(float z)  { return __builtin_amdgcn_rcpf(z); }
__device__ __forceinline__ float fsigmoid(float z) {
  return frcp(1.0f + fexp2(-1.44269504f * z));
}
__device__ __forceinline__ float ftanh(float z) {
  return 1.0f - 2.0f * frcp(1.0f + fexp2(2.88539008f * z));
}

// ---- repack: weights -> bf16 MFMA A-fragments, biases -> combined fp32 ----
__global__ void repack_kernel(const float* __restrict__ W_i, const float* __restrict__ W_c,
                              const float* __restrict__ W_o, const float* __restrict__ fc_W,
                              const float* __restrict__ bg_i, const float* __restrict__ bg_c,
                              const float* __restrict__ bg_o,
                              const float* __restrict__ b_i, const float* __restrict__ b_c,
                              const float* __restrict__ b_o, const float* __restrict__ wc_o,
                              const float* __restrict__ fc_b,
                              short* __restrict__ wfrag, short* __restrict__ fcfrag,
                              float* __restrict__ bias) {
  int tid = blockIdx.x * blockDim.x + threadIdx.x;
  const int total1 = WFRAG_ELEMS;
  const int total2 = FCFRAG_ELEMS;
  for (int e = tid; e < total1 + total2 + HID + OUT_DIM; e += gridDim.x * blockDim.x) {
    if (e < total1) {
      // A-frag of first GEMM: A = Wcat^T (384x64). tile t: rows 16t+cidx; k=32s+8q+j
      int j = e & 7, lane = (e >> 3) & 63, s = (e >> 9) & 1, t = e >> 10;
      int q = lane >> 4, cidx = lane & 15;
      int gate = t >> 3;                       // 0:W_i 1:W_c 2:W_o
      int h = (t & 7) * 16 + cidx;
      int feat = 32 * s + 8 * q + j;
      const float* W = (gate == 0) ? W_i : ((gate == 1) ? W_c : W_o);
      wfrag[e] = f2bf(W[feat * HID + h]);
    } else if (e < total1 + total2) {
      // A-frag of second GEMM: A = fc_W^T (64x128). tile t: rows 16t+cidx; k=32s+8q+j
      int e2 = e - total1;
      int j = e2 & 7, lane = (e2 >> 3) & 63, s = (e2 >> 9) & 3, t = e2 >> 11;
      int q = lane >> 4, cidx = lane & 15;
      int od = 16 * t + cidx;
      int hid = 32 * s + 8 * q + j;
      fcfrag[e2] = f2bf(fc_W[hid * OUT_DIM + od]);
    } else if (e < total1 + total2 + HID) {
      int h = e - total1 - total2;
      bias[h]           = bg_i[h] + b_i[h];
      bias[HID + h]     = bg_c[h] + b_c[h];
      bias[2 * HID + h] = bg_o[h] + b_o[h];
      bias[3 * HID + h] = wc_o[h];
    } else {
      int h2 = e - total1 - total2 - HID;
      bias[4 * HID + h2] = fc_b[h2];
    }
  }
}

// ---- fused main kernel: 4 waves/WG, each wave owns 32 rows, no barriers ----
__global__ __launch_bounds__(256) void gclstm_fused(
    const float* __restrict__ x, const short* __restrict__ wfrag,
    const short* __restrict__ fcfrag, const float* __restrict__ bias,
    float* __restrict__ out) {
  __shared__ short Hlds[4 * 32 * 128];   // 32 KB, wave-private 8KB slices
  const int lane = threadIdx.x & 63;
  const int wslot = threadIdx.x >> 6;
  const int wid = blockIdx.x * 4 + wslot;
  const int row0 = wid * 32;
  if (row0 >= N_ROWS) return;            // N_ROWS % 32 == 0, full tiles only
  const int q = lane >> 4, cidx = lane & 15;
  short* hbase = Hlds + wslot * (32 * 128);
  const int swz = (cidx & 7) << 3;       // element-index XOR swizzle (bytes<<1)

  // x B-fragments: B = x^T; lane supplies col=cidx (row row0+16m+cidx), k=32s+8q+j
  short8 bx[2][2];
#pragma unroll
  for (int m = 0; m < 2; ++m) {
    const float* xr = x + (size_t)(row0 + 16 * m + cidx) * IN_DIM + 8 * q;
#pragma unroll
    for (int s = 0; s < 2; ++s) {
      f32x4 f0 = *(const f32x4*)(xr + 32 * s);
      f32x4 f1 = *(const f32x4*)(xr + 32 * s + 4);
      short8 v;
      v[0] = f2bf(f0[0]); v[1] = f2bf(f0[1]); v[2] = f2bf(f0[2]); v[3] = f2bf(f0[3]);
      v[4] = f2bf(f1[0]); v[5] = f2bf(f1[1]); v[6] = f2bf(f1[2]); v[7] = f2bf(f1[3]);
      bx[m][s] = v;
    }
  }

  const float* Bi  = bias;
  const float* Bc  = bias + HID;
  const float* Bo  = bias + 2 * HID;
  const float* Wco = bias + 3 * HID;
  const float* Fcb = bias + 4 * HID;
  const f32x4 zero4 = {0.f, 0.f, 0.f, 0.f};

#pragma unroll
  for (int g = 0; g < 8; ++g) {
    f32x4 acc[3][2];
#pragma unroll
    for (int a = 0; a < 3; ++a) { acc[a][0] = zero4; acc[a][1] = zero4; }
#pragma unroll
    for (int s = 0; s < 2; ++s) {
      short8 ai = *(const short8*)(wfrag + (((g     ) * 2 + s) * 64 + lane) * 8);
      short8 ac = *(const short8*)(wfrag + (((g +  8) * 2 + s) * 64 + lane) * 8);
      short8 ao = *(const short8*)(wfrag + (((g + 16) * 2 + s) * 64 + lane) * 8);
#pragma unroll
      for (int m = 0; m < 2; ++m) {
        acc[0][m] = __builtin_amdgcn_mfma_f32_16x16x32_bf16(ai, bx[m][s], acc[0][m], 0, 0, 0);
        acc[1][m] = __builtin_amdgcn_mfma_f32_16x16x32_bf16(ac, bx[m][s], acc[1][m], 0, 0, 0);
        acc[2][m] = __builtin_amdgcn_mfma_f32_16x16x32_bf16(ao, bx[m][s], acc[2][m], 0, 0, 0);
      }
    }
    // D tile: lane holds rows h = 16g+4q+r (r=0..3), col = xrow 16m+cidx
    const int h0 = g * 16 + 4 * q;
    f32x4 vbi = *(const f32x4*)(Bi + h0);
    f32x4 vbc = *(const f32x4*)(Bc + h0);
    f32x4 vbo = *(const f32x4*)(Bo + h0);
    f32x4 vwc = *(const f32x4*)(Wco + h0);
#pragma unroll
    for (int m = 0; m < 2; ++m) {
      short4_t hw;
#pragma unroll
      for (int r = 0; r < 4; ++r) {
        float gi = fsigmoid(acc[0][m][r] + vbi[r]);
        float gt = ftanh(acc[1][m][r] + vbc[r]);
        float C  = gi * gt;
        float go = fsigmoid(acc[2][m][r] + vbo[r] + vwc[r] * C);
        hw[r] = f2bf(go * ftanh(C));
      }
      const int xrow = 16 * m + cidx;
      *(short4_t*)(hbase + (((xrow * 128 + h0) ^ swz))) = hw;   // ds_write_b64
    }
  }

  // second GEMM: out^T = fc_W^T @ H^T ; B-frag = H^T from wave-private LDS
  f32x4 oacc[4][2];
#pragma unroll
  for (int t = 0; t < 4; ++t) { oacc[t][0] = zero4; oacc[t][1] = zero4; }
#pragma unroll
  for (int s = 0; s < 4; ++s) {
    short8 bh[2];
#pragma unroll
    for (int m = 0; m < 2; ++m) {
      const int xrow = 16 * m + cidx;
      bh[m] = *(const short8*)(hbase + (((xrow * 128 + 32 * s + 8 * q) ^ swz)));  // ds_read_b128
    }
#pragma unroll
    for (int t = 0; t < 4; ++t) {
      short8 af = *(const short8*)(fcfrag + ((t * 4 + s) * 64 + lane) * 8);
#pragma unroll
      for (int m = 0; m < 2; ++m)
        oacc[t][m] = __builtin_amdgcn_mfma_f32_16x16x32_bf16(af, bh[m], oacc[t][m], 0, 0, 0);
    }
  }

  // epilogue: lane holds out^T[od=16t+4q+r][xrow=16m+cidx]; float4 stores
#pragma unroll
  for (int t = 0; t < 4; ++t) {
    const int od0 = 16 * t + 4 * q;
    f32x4 fb = *(const f32x4*)(Fcb + od0);
#pragma unroll
    for (int m = 0; m < 2; ++m) {
      f32x4 v = oacc[t][m] + fb;
      *(f32x4*)(out + (size_t)(row0 + 16 * m + cidx) * OUT_DIM + od0) = v;
    }
  }
}

extern "C" void kernel_launch(void* const* d_in, const int* in_sizes, int n_in,
                              void* d_out, int out_size, void* d_ws, size_t ws_size,
                              hipStream_t stream) {
  (void)in_sizes; (void)n_in; (void)out_size; (void)ws_size;
  const float* x    = (const float*)d_in[0];
  const float* W_i  = (const float*)d_in[3];
  const float* W_c  = (const float*)d_in[5];
  const float* W_o  = (const float*)d_in[6];
  const float* bg_i = (const float*)d_in[11];
  const float* bg_c = (const float*)d_in[13];
  const float* bg_o = (const float*)d_in[14];
  const float* wc_o = (const float*)d_in[17];
  const float* b_i  = (const float*)d_in[18];
  const float* b_c  = (const float*)d_in[20];
  const float* b_o  = (const float*)d_in[21];
  const float* fc_W = (const float*)d_in[22];
  const float* fc_b = (const float*)d_in[23];

  short* wfrag  = (short*)d_ws;
  short* fcfrag = (short*)((char*)d_ws + FCFRAG_OFF);
  float* bias   = (float*)((char*)d_ws + BIAS_OFF);

  repack_kernel<<<dim3(64), dim3(256), 0, stream>>>(
      W_i, W_c, W_o, fc_W, bg_i, bg_c, bg_o, b_i, b_c, b_o, wc_o, fc_b,
      wfrag, fcfrag, bias);

  const int nchunks = (N_ROWS + 31) / 32;   // 6250
  const int nwg = (nchunks + 3) / 4;        // 1563
  gclstm_fused<<<dim3(nwg), dim3(256), 0, stream>>>(
      x, wfrag, fcfrag, bias, (float*)d_out);
}